// Round 1
// baseline (84.529 us; speedup 1.0000x reference)
//
#include <hip/hip_runtime.h>

// Problem constants (fixed by reference)
#define NB 8
#define NN 2048
#define KK 64
#define VV 64
#define TO 64              // o-columns per block
#define IT 64              // i-rows per step
#define NSTEP (NN / IT)    // 32
#define SCALE 0.18033688011112043f  // (1/sqrt(64)) * log2(e)

typedef __bf16 bfrag __attribute__((ext_vector_type(8)));
typedef float f32x4 __attribute__((ext_vector_type(4)));
typedef unsigned short u16x4 __attribute__((ext_vector_type(4)));
typedef unsigned short u16x8 __attribute__((ext_vector_type(8)));

// fp32 -> bf16 round-to-nearest-even (bit trick)
__device__ __forceinline__ unsigned short bf16r(float f) {
  unsigned u = __float_as_uint(f);
  u += 0x7fffu + ((u >> 16) & 1u);
  return (unsigned short)(u >> 16);
}

// LDS byte offset within a [64][64]-bf16 tile (128B rows) with XOR swizzle
// (G4: breaks the 16-way bank conflict of stride-128B column reads)
__device__ __forceinline__ int swz(int row, int colByte) {
  return row * 128 + (colByte ^ ((row & 7) << 4));
}

__device__ __forceinline__ bfrag lds_frag(const unsigned short* base, int row, int colByte) {
  return *reinterpret_cast<const bfrag*>(reinterpret_cast<const char*>(base) + swz(row, colByte));
}

// ---- staging helpers: 16 consecutive fp32 -> 16 bf16 into one LDS row ----
struct KS { float4 f[4]; };
__device__ __forceinline__ void k_load(KS& s, const float* __restrict__ g) {
  const float4* p = reinterpret_cast<const float4*>(g);
  s.f[0] = p[0]; s.f[1] = p[1]; s.f[2] = p[2]; s.f[3] = p[3];
}
__device__ __forceinline__ void k_write(const KS& s, unsigned short* lds, int row, int colByte) {
  const float* f = reinterpret_cast<const float*>(&s.f[0]);
  u16x8 a, b;
#pragma unroll
  for (int j = 0; j < 8; ++j) a[j] = bf16r(f[j]);
#pragma unroll
  for (int j = 0; j < 8; ++j) b[j] = bf16r(f[8 + j]);
  *reinterpret_cast<u16x8*>(reinterpret_cast<char*>(lds) + swz(row, colByte)) = a;
  *reinterpret_cast<u16x8*>(reinterpret_cast<char*>(lds) + swz(row, colByte + 16)) = b;
}

// ---- V staging: two consecutive i-rows x 8 v -> transposed Vt[v][i] (4B packed writes) ----
struct VS { float4 f[4]; };
__device__ __forceinline__ void v_load(VS& s, const float* __restrict__ g) {
  const float4* p = reinterpret_cast<const float4*>(g);
  s.f[0] = p[0]; s.f[1] = p[1];
  const float4* q = reinterpret_cast<const float4*>(g + VV);
  s.f[2] = q[0]; s.f[3] = q[1];
}
__device__ __forceinline__ void v_write(const VS& s, unsigned short* lds, int il, int v0) {
  const float* lo = reinterpret_cast<const float*>(&s.f[0]);
  const float* hi = reinterpret_cast<const float*>(&s.f[2]);
#pragma unroll
  for (int j = 0; j < 8; ++j) {
    unsigned pk = (unsigned)bf16r(lo[j]) | ((unsigned)bf16r(hi[j]) << 16);
    *reinterpret_cast<unsigned*>(reinterpret_cast<char*>(lds) + swz(v0 + j, il * 2)) = pk;
  }
}

__global__ void __launch_bounds__(256) attn_fused(
    const float* __restrict__ key, const float* __restrict__ query,
    const float* __restrict__ value, float* __restrict__ out)
{
  __shared__ __align__(16) unsigned short Kt[2][IT * KK];
  __shared__ __align__(16) unsigned short Vt[2][VV * IT];
  __shared__ __align__(16) unsigned short Qt[TO * KK];
  __shared__ __align__(16) unsigned short Et[TO * IT];
  __shared__ float Red[4][TO];
  __shared__ float BcD[TO];
  __shared__ float BcN[TO];

  const int tid  = threadIdx.x;
  const int lane = tid & 63;
  const int wv   = tid >> 6;     // wave 0..3
  const int l15  = lane & 15;
  const int l4   = lane >> 4;

  // batch -> XCD (blockIdx % 8 round-robins XCDs): same-batch blocks share L2
  const int b  = blockIdx.x & 7;
  const int o0 = (blockIdx.x >> 3) * TO;

  const float* Kg = key   + (size_t)b * NN * KK;
  const float* Qg = query + (size_t)b * NN * KK;
  const float* Vg = value + (size_t)b * NN * VV;
  float* outV = out + (size_t)b * VV * NN;
  float* outW = out + (size_t)NB * VV * NN + (size_t)b * NN * NN;

  // staging coordinates
  const int krow = tid >> 2;          // 0..63 (row within tile)
  const int kel  = (tid & 3) * 16;    // first element (of 16) in row
  const int kcb  = (tid & 3) * 32;    // its byte offset
  const int vil  = (tid & 31) * 2;    // i-pair base within tile
  const int vv0  = (tid >> 5) * 8;    // v group (8 v's)

  // ---- stage Q tile (once) ----
  {
    KS qs;
    k_load(qs, Qg + (size_t)(o0 + krow) * KK + kel);
    k_write(qs, Qt, krow, kcb);
  }
  // ---- preload tile 0 ----
  KS ks; VS vs;
  k_load(ks, Kg + (size_t)krow * KK + kel);
  v_load(vs, Vg + (size_t)vil * VV + vv0);
  k_write(ks, Kt[0], krow, kcb);
  v_write(vs, Vt[0], vil, vv0);
  __syncthreads();

  f32x4 uacc[4];
  float Dacc[4] = {0.f, 0.f, 0.f, 0.f};
#pragma unroll
  for (int s = 0; s < 4; ++s) { f32x4 z = {0.f, 0.f, 0.f, 0.f}; uacc[s] = z; }

  // =============== PASS 1: D[o] and U[v][o] (unnormalized PV) ===============
  for (int t = 0; t < NSTEP; ++t) {
    const int c = t & 1;
    if (t + 1 < NSTEP) {  // issue next-tile loads early (hide under MFMA/exp)
      k_load(ks, Kg + (size_t)((t + 1) * IT + krow) * KK + kel);
      v_load(vs, Vg + (size_t)((t + 1) * IT + vil) * VV + vv0);
    }
    // S = K_tile . Q^T   (wave wv owns i-strip wv*16..+15, all 64 o)
    bfrag a0 = lds_frag(Kt[c], wv * 16 + l15, l4 * 16);
    bfrag a1 = lds_frag(Kt[c], wv * 16 + l15, 64 + l4 * 16);
#pragma unroll
    for (int s = 0; s < 4; ++s) {
      bfrag b0 = lds_frag(Qt, s * 16 + l15, l4 * 16);
      bfrag b1 = lds_frag(Qt, s * 16 + l15, 64 + l4 * 16);
      f32x4 z = {0.f, 0.f, 0.f, 0.f};
      z = __builtin_amdgcn_mfma_f32_16x16x32_bf16(a0, b0, z, 0, 0, 0);
      z = __builtin_amdgcn_mfma_f32_16x16x32_bf16(a1, b1, z, 0, 0, 0);
      // e = exp(s/8); accumulate D; write Et[o][i] (bf16) for PV
      f32x4 e;
#pragma unroll
      for (int r = 0; r < 4; ++r) e[r] = exp2f(z[r] * SCALE);
      Dacc[s] += e[0] + e[1] + e[2] + e[3];
      u16x4 pk;
#pragma unroll
      for (int r = 0; r < 4; ++r) pk[r] = bf16r(e[r]);
      *reinterpret_cast<u16x4*>(reinterpret_cast<char*>(Et) +
                                swz(s * 16 + l15, wv * 32 + l4 * 8)) = pk;
    }
    // stage next tiles into the other buffer (no clobber of current reads)
    if (t + 1 < NSTEP) {
      k_write(ks, Kt[c ^ 1], krow, kcb);
      v_write(vs, Vt[c ^ 1], vil, vv0);
    }
    __syncthreads();   // Et + next tiles ready
    // U[v][o] += V^T . E   (wave wv owns v-strip wv*16..+15)
    bfrag va0 = lds_frag(Vt[c], wv * 16 + l15, l4 * 16);
    bfrag va1 = lds_frag(Vt[c], wv * 16 + l15, 64 + l4 * 16);
#pragma unroll
    for (int s = 0; s < 4; ++s) {
      bfrag e0 = lds_frag(Et, s * 16 + l15, l4 * 16);
      bfrag e1 = lds_frag(Et, s * 16 + l15, 64 + l4 * 16);
      uacc[s] = __builtin_amdgcn_mfma_f32_16x16x32_bf16(va0, e0, uacc[s], 0, 0, 0);
      uacc[s] = __builtin_amdgcn_mfma_f32_16x16x32_bf16(va1, e1, uacc[s], 0, 0, 0);
    }
    __syncthreads();   // PV done before Et is rewritten next step
  }

  // ---- reduce D over waves/lanes -> invD[o] ----
#pragma unroll
  for (int s = 0; s < 4; ++s) {
    float d = Dacc[s];
    d += __shfl_xor(d, 16, 64);
    d += __shfl_xor(d, 32, 64);
    if (lane < 16) Red[wv][s * 16 + lane] = d;
  }
  __syncthreads();
  if (tid < TO) {
    float D = Red[0][tid] + Red[1][tid] + Red[2][tid] + Red[3][tid];
    BcD[tid] = 1.0f / D;
  }
  __syncthreads();
  float invd[4];
#pragma unroll
  for (int s = 0; s < 4; ++s) invd[s] = BcD[s * 16 + l15];
  __syncthreads();

  // ---- L2 norm over v (softmax denom cancels) -> write values[b][v][o] ----
#pragma unroll
  for (int s = 0; s < 4; ++s) {
    float ss = uacc[s][0] * uacc[s][0] + uacc[s][1] * uacc[s][1] +
               uacc[s][2] * uacc[s][2] + uacc[s][3] * uacc[s][3];
    ss += __shfl_xor(ss, 16, 64);
    ss += __shfl_xor(ss, 32, 64);
    if (lane < 16) Red[wv][s * 16 + lane] = ss;
  }
  __syncthreads();
  if (tid < TO) {
    float n = Red[0][tid] + Red[1][tid] + Red[2][tid] + Red[3][tid];
    BcN[tid] = 1.0f / (sqrtf(n) + 1e-12f);
  }
  __syncthreads();
#pragma unroll
  for (int s = 0; s < 4; ++s) {
    float inn = BcN[s * 16 + l15];
    float* vp = outV + (size_t)(wv * 16 + l4 * 4) * NN + o0 + s * 16 + l15;
#pragma unroll
    for (int r = 0; r < 4; ++r) vp[(size_t)r * NN] = uacc[s][r] * inn;
  }

  // =============== PASS 2: recompute S, write weights = e * invD ===============
  k_load(ks, Kg + (size_t)krow * KK + kel);
  k_write(ks, Kt[0], krow, kcb);
  __syncthreads();
  for (int t = 0; t < NSTEP; ++t) {
    const int c = t & 1;
    if (t + 1 < NSTEP)
      k_load(ks, Kg + (size_t)((t + 1) * IT + krow) * KK + kel);
    bfrag a0 = lds_frag(Kt[c], wv * 16 + l15, l4 * 16);
    bfrag a1 = lds_frag(Kt[c], wv * 16 + l15, 64 + l4 * 16);
#pragma unroll
    for (int s = 0; s < 4; ++s) {
      bfrag b0 = lds_frag(Qt, s * 16 + l15, l4 * 16);
      bfrag b1 = lds_frag(Qt, s * 16 + l15, 64 + l4 * 16);
      f32x4 z = {0.f, 0.f, 0.f, 0.f};
      z = __builtin_amdgcn_mfma_f32_16x16x32_bf16(a0, b0, z, 0, 0, 0);
      z = __builtin_amdgcn_mfma_f32_16x16x32_bf16(a1, b1, z, 0, 0, 0);
      float* wp = outW + (size_t)(t * IT + wv * 16 + l4 * 4) * NN + o0 + s * 16 + l15;
#pragma unroll
      for (int r = 0; r < 4; ++r)
        wp[(size_t)r * NN] = exp2f(z[r] * SCALE) * invd[s];
    }
    if (t + 1 < NSTEP) k_write(ks, Kt[c ^ 1], krow, kcb);
    __syncthreads();
  }
}

extern "C" void kernel_launch(void* const* d_in, const int* in_sizes, int n_in,
                              void* d_out, int out_size, void* d_ws, size_t ws_size,
                              hipStream_t stream) {
  (void)in_sizes; (void)n_in; (void)d_ws; (void)ws_size; (void)out_size;
  const float* key   = (const float*)d_in[0];
  const float* query = (const float*)d_in[1];
  const float* value = (const float*)d_in[2];
  float* out = (float*)d_out;
  attn_fused<<<dim3(NB * (NN / TO)), dim3(256), 0, stream>>>(key, query, value, out);
}

// Round 2
// 70.970 us; speedup vs baseline: 1.1910x; 1.1910x over previous
//
#include <hip/hip_runtime.h>

// Problem constants (fixed by reference)
#define NB 8
#define NN 2048
#define KK 64
#define VV 64
#define SCALE 0.18033688011112043f  // (1/sqrt(64)) * log2(e)

typedef __bf16 bfrag __attribute__((ext_vector_type(8)));
typedef float f32x4 __attribute__((ext_vector_type(4)));
typedef unsigned short u16x4 __attribute__((ext_vector_type(4)));
typedef unsigned short u16x8 __attribute__((ext_vector_type(8)));

// fp32 -> bf16 round-to-nearest-even
__device__ __forceinline__ unsigned short bf16r(float f) {
  unsigned u = __float_as_uint(f);
  u += 0x7fffu + ((u >> 16) & 1u);
  return (unsigned short)(u >> 16);
}

// LDS byte offset within a tile with 128B rows, XOR-swizzled (G4)
__device__ __forceinline__ int swz(int row, int colByte) {
  return row * 128 + (colByte ^ ((row & 7) << 4));
}

__device__ __forceinline__ bfrag lds_frag(const unsigned short* base, int row, int colByte) {
  return *reinterpret_cast<const bfrag*>(reinterpret_cast<const char*>(base) + swz(row, colByte));
}

// ---- staging: 16 consecutive fp32 -> 16 bf16 into one LDS row ----
struct KS { float4 f[4]; };
__device__ __forceinline__ void k_load(KS& s, const float* __restrict__ g) {
  const float4* p = reinterpret_cast<const float4*>(g);
  s.f[0] = p[0]; s.f[1] = p[1]; s.f[2] = p[2]; s.f[3] = p[3];
}
__device__ __forceinline__ void k_write(const KS& s, unsigned short* lds, int row, int colByte) {
  const float* f = reinterpret_cast<const float*>(&s.f[0]);
  u16x8 a, b;
#pragma unroll
  for (int j = 0; j < 8; ++j) a[j] = bf16r(f[j]);
#pragma unroll
  for (int j = 0; j < 8; ++j) b[j] = bf16r(f[8 + j]);
  *reinterpret_cast<u16x8*>(reinterpret_cast<char*>(lds) + swz(row, colByte)) = a;
  *reinterpret_cast<u16x8*>(reinterpret_cast<char*>(lds) + swz(row, colByte + 16)) = b;
}

// ---- V staging: two consecutive i-rows x 8 v -> transposed Vt[v][i] ----
struct VS { float4 f[4]; };
__device__ __forceinline__ void v_load(VS& s, const float* __restrict__ g) {
  const float4* p = reinterpret_cast<const float4*>(g);
  s.f[0] = p[0]; s.f[1] = p[1];
  const float4* q = reinterpret_cast<const float4*>(g + VV);
  s.f[2] = q[0]; s.f[3] = q[1];
}
__device__ __forceinline__ void v_write(const VS& s, unsigned short* lds, int il, int v0) {
  const float* lo = reinterpret_cast<const float*>(&s.f[0]);
  const float* hi = reinterpret_cast<const float*>(&s.f[2]);
#pragma unroll
  for (int j = 0; j < 8; ++j) {
    unsigned pk = (unsigned)bf16r(lo[j]) | ((unsigned)bf16r(hi[j]) << 16);
    *reinterpret_cast<unsigned*>(reinterpret_cast<char*>(lds) + swz(v0 + j, il * 2)) = pk;
  }
}

// =====================================================================
// K1: per (b, o-tile of 64, i-chunk of 512) compute partial D[64] and
// partial U[64][64], write to scratch (head of the weights region).
// Single-buffered LDS (33KB -> 4 blocks/CU), 2 barriers/step.
// =====================================================================
#define CHUNK 512
#define IT 64
#define K1STEPS (CHUNK / IT)   // 8
#define SCR_STRIDE 4160        // 64*64 U + 64 D floats per chunk

__global__ void __launch_bounds__(256) attn_pass1(
    const float* __restrict__ key, const float* __restrict__ query,
    const float* __restrict__ value, float* __restrict__ scratch)
{
  __shared__ __align__(16) unsigned short Kt[IT * KK];
  __shared__ __align__(16) unsigned short Vt[VV * IT];
  __shared__ __align__(16) unsigned short Qt[64 * KK];
  __shared__ __align__(16) unsigned short Et[64 * IT];
  __shared__ float Red[4][64];

  const int tid  = threadIdx.x;
  const int lane = tid & 63;
  const int wv   = tid >> 6;
  const int l15  = lane & 15;
  const int l4   = lane >> 4;

  const int b    = blockIdx.x & 7;          // batch -> XCD
  const int rest = blockIdx.x >> 3;
  const int ot   = rest & 31;               // o-tile (64 cols)
  const int ci   = rest >> 5;               // i-chunk (512 rows)
  const int o0   = ot * 64;
  const int ib0  = ci * CHUNK;

  const float* Kg = key   + (size_t)b * NN * KK;
  const float* Qg = query + (size_t)b * NN * KK;
  const float* Vg = value + (size_t)b * NN * VV;
  float* scr = scratch + (size_t)((b * 32 + ot) * 4 + ci) * SCR_STRIDE;

  const int krow = tid >> 2;          // 0..63
  const int kel  = (tid & 3) * 16;
  const int kcb  = (tid & 3) * 32;
  const int vil  = (tid & 31) * 2;
  const int vv0  = (tid >> 5) * 8;

  // stage Q tile + tile 0 of K/V
  {
    KS qs;
    k_load(qs, Qg + (size_t)(o0 + krow) * KK + kel);
    k_write(qs, Qt, krow, kcb);
  }
  KS ks; VS vs;
  k_load(ks, Kg + (size_t)(ib0 + krow) * KK + kel);
  v_load(vs, Vg + (size_t)(ib0 + vil) * VV + vv0);
  k_write(ks, Kt, krow, kcb);
  v_write(vs, Vt, vil, vv0);
  __syncthreads();

  f32x4 uacc[4];
  float Dacc[4] = {0.f, 0.f, 0.f, 0.f};
#pragma unroll
  for (int s = 0; s < 4; ++s) { f32x4 z = {0.f, 0.f, 0.f, 0.f}; uacc[s] = z; }

  for (int t = 0; t < K1STEPS; ++t) {
    if (t + 1 < K1STEPS) {
      k_load(ks, Kg + (size_t)(ib0 + (t + 1) * IT + krow) * KK + kel);
      v_load(vs, Vg + (size_t)(ib0 + (t + 1) * IT + vil) * VV + vv0);
    }
    // QK: S = K_tile . Q^T ; e = exp ; accumulate D ; write Et
    bfrag a0 = lds_frag(Kt, wv * 16 + l15, l4 * 16);
    bfrag a1 = lds_frag(Kt, wv * 16 + l15, 64 + l4 * 16);
#pragma unroll
    for (int s = 0; s < 4; ++s) {
      bfrag b0 = lds_frag(Qt, s * 16 + l15, l4 * 16);
      bfrag b1 = lds_frag(Qt, s * 16 + l15, 64 + l4 * 16);
      f32x4 z = {0.f, 0.f, 0.f, 0.f};
      z = __builtin_amdgcn_mfma_f32_16x16x32_bf16(a0, b0, z, 0, 0, 0);
      z = __builtin_amdgcn_mfma_f32_16x16x32_bf16(a1, b1, z, 0, 0, 0);
      f32x4 e;
#pragma unroll
      for (int r = 0; r < 4; ++r) e[r] = exp2f(z[r] * SCALE);
      Dacc[s] += e[0] + e[1] + e[2] + e[3];
      u16x4 pk;
#pragma unroll
      for (int r = 0; r < 4; ++r) pk[r] = bf16r(e[r]);
      *reinterpret_cast<u16x4*>(reinterpret_cast<char*>(Et) +
                                swz(s * 16 + l15, wv * 32 + l4 * 8)) = pk;
    }
    __syncthreads();   // A: Et ready; Kt reads complete
    if (t + 1 < K1STEPS) k_write(ks, Kt, krow, kcb);   // restage K (read next QK)
    // PV: U += V^T . E
    bfrag va0 = lds_frag(Vt, wv * 16 + l15, l4 * 16);
    bfrag va1 = lds_frag(Vt, wv * 16 + l15, 64 + l4 * 16);
#pragma unroll
    for (int s = 0; s < 4; ++s) {
      bfrag e0 = lds_frag(Et, s * 16 + l15, l4 * 16);
      bfrag e1 = lds_frag(Et, s * 16 + l15, 64 + l4 * 16);
      uacc[s] = __builtin_amdgcn_mfma_f32_16x16x32_bf16(va0, e0, uacc[s], 0, 0, 0);
      uacc[s] = __builtin_amdgcn_mfma_f32_16x16x32_bf16(va1, e1, uacc[s], 0, 0, 0);
    }
    __syncthreads();   // B: Vt/Et reads complete; staged Kt visible
    if (t + 1 < K1STEPS) v_write(vs, Vt, vil, vv0);    // restage V (read next PV)
  }

  // partial U -> scratch  (U[v][o] layout, v-major)
#pragma unroll
  for (int s = 0; s < 4; ++s)
#pragma unroll
    for (int r = 0; r < 4; ++r)
      scr[(wv * 16 + l4 * 4 + r) * 64 + s * 16 + l15] = uacc[s][r];

  // partial D -> scratch
#pragma unroll
  for (int s = 0; s < 4; ++s) {
    float d = Dacc[s];
    d += __shfl_xor(d, 16, 64);
    d += __shfl_xor(d, 32, 64);
    if (lane < 16) Red[wv][s * 16 + lane] = d;
  }
  __syncthreads();
  if (tid < 64)
    scr[4096 + tid] = Red[0][tid] + Red[1][tid] + Red[2][tid] + Red[3][tid];
}

// =====================================================================
// K2: reduce 4 chunks -> L2-normalized values + invD (to d_ws)
// grid 256 = (b, o-tile), 256 threads
// =====================================================================
__global__ void __launch_bounds__(256) attn_reduce(
    const float* __restrict__ scratch, float* __restrict__ outV,
    float* __restrict__ invD)
{
  __shared__ float R2[4][64];
  __shared__ float Nn[64];

  const int tid = threadIdx.x;
  const int b   = blockIdx.x & 7;
  const int ot  = blockIdx.x >> 3;
  const float* base = scratch + (size_t)(b * 32 + ot) * 4 * SCR_STRIDE;

  const int ol = tid & 63;    // o within tile (fixed per thread)
  const int vb = tid >> 6;    // v base group

  float u[16];
#pragma unroll
  for (int j = 0; j < 16; ++j) u[j] = 0.f;
#pragma unroll
  for (int c = 0; c < 4; ++c) {
    const float* p = base + c * SCR_STRIDE;
#pragma unroll
    for (int j = 0; j < 16; ++j) u[j] += p[tid + j * 256];  // v = vb + 4j, o = ol
  }
  float ssq = 0.f;
#pragma unroll
  for (int j = 0; j < 16; ++j) ssq += u[j] * u[j];
  R2[vb][ol] = ssq;
  __syncthreads();
  if (tid < 64) {
    float n = R2[0][tid] + R2[1][tid] + R2[2][tid] + R2[3][tid];
    Nn[tid] = 1.f / (sqrtf(n) + 1e-12f);
    float D = 0.f;
#pragma unroll
    for (int c = 0; c < 4; ++c) D += base[c * SCR_STRIDE + 4096 + tid];
    invD[b * NN + ot * 64 + tid] = 1.f / D;
  }
  __syncthreads();
  const float inn = Nn[ol];
  float* vp = outV + (size_t)b * VV * NN + ot * 64 + ol;
#pragma unroll
  for (int j = 0; j < 16; ++j)
    vp[(size_t)(vb + 4 * j) * NN] = u[j] * inn;
}

// =====================================================================
// K3: weights = exp(K.Q^T/8) * invD, 128x128 tile per block
// grid 2048 = (b, 16 i-tiles, 16 o-tiles), 256 threads, 32KB LDS
// =====================================================================
__global__ void __launch_bounds__(256) attn_weights(
    const float* __restrict__ key, const float* __restrict__ query,
    const float* __restrict__ invD, float* __restrict__ outWall)
{
  __shared__ __align__(16) unsigned short Kt2[128 * 64];
  __shared__ __align__(16) unsigned short Qt2[128 * 64];

  const int tid  = threadIdx.x;
  const int lane = tid & 63;
  const int wv   = tid >> 6;
  const int l15  = lane & 15;
  const int l4   = lane >> 4;

  const int b    = blockIdx.x & 7;           // batch -> XCD
  const int rest = blockIdx.x >> 3;
  const int it   = rest & 15;                // i-tile (128)
  const int ot   = rest >> 4;                // o-tile (128)

  const float* Kg = key   + (size_t)b * NN * KK;
  const float* Qg = query + (size_t)b * NN * KK;
  float* outW = outWall + (size_t)b * NN * NN;

  const int krow = tid >> 2;
  const int kel  = (tid & 3) * 16;
  const int kcb  = (tid & 3) * 32;

  KS s0, s1, s2, s3;
  k_load(s0, Kg + (size_t)(it * 128 + krow) * KK + kel);
  k_load(s1, Kg + (size_t)(it * 128 + 64 + krow) * KK + kel);
  k_load(s2, Qg + (size_t)(ot * 128 + krow) * KK + kel);
  k_load(s3, Qg + (size_t)(ot * 128 + 64 + krow) * KK + kel);
  k_write(s0, Kt2, krow, kcb);
  k_write(s1, Kt2, krow + 64, kcb);
  k_write(s2, Qt2, krow, kcb);
  k_write(s3, Qt2, krow + 64, kcb);

  float invd[8];
#pragma unroll
  for (int s = 0; s < 8; ++s)
    invd[s] = invD[b * NN + ot * 128 + s * 16 + l15];
  __syncthreads();

  // wave wv owns i rows [wv*32, wv*32+32)
  bfrag a0[2], a1[2];
#pragma unroll
  for (int m = 0; m < 2; ++m) {
    a0[m] = lds_frag(Kt2, wv * 32 + m * 16 + l15, l4 * 16);
    a1[m] = lds_frag(Kt2, wv * 32 + m * 16 + l15, 64 + l4 * 16);
  }
  f32x4 acc[2][8];
#pragma unroll
  for (int m = 0; m < 2; ++m)
#pragma unroll
    for (int s = 0; s < 8; ++s) { f32x4 z = {0.f, 0.f, 0.f, 0.f}; acc[m][s] = z; }

#pragma unroll
  for (int s = 0; s < 8; ++s) {
    bfrag b0 = lds_frag(Qt2, s * 16 + l15, l4 * 16);
    bfrag b1 = lds_frag(Qt2, s * 16 + l15, 64 + l4 * 16);
#pragma unroll
    for (int m = 0; m < 2; ++m) {
      acc[m][s] = __builtin_amdgcn_mfma_f32_16x16x32_bf16(a0[m], b0, acc[m][s], 0, 0, 0);
      acc[m][s] = __builtin_amdgcn_mfma_f32_16x16x32_bf16(a1[m], b1, acc[m][s], 0, 0, 0);
    }
  }

#pragma unroll
  for (int m = 0; m < 2; ++m)
#pragma unroll
    for (int s = 0; s < 8; ++s) {
      float* wp = outW + (size_t)(it * 128 + wv * 32 + m * 16 + l4 * 4) * NN +
                  ot * 128 + s * 16 + l15;
#pragma unroll
      for (int r = 0; r < 4; ++r)
        wp[(size_t)r * NN] = exp2f(acc[m][s][r] * SCALE) * invd[s];
    }
}

extern "C" void kernel_launch(void* const* d_in, const int* in_sizes, int n_in,
                              void* d_out, int out_size, void* d_ws, size_t ws_size,
                              hipStream_t stream) {
  (void)in_sizes; (void)n_in; (void)ws_size; (void)out_size;
  const float* key   = (const float*)d_in[0];
  const float* query = (const float*)d_in[1];
  const float* value = (const float*)d_in[2];
  float* out  = (float*)d_out;
  float* outV = out;                                  // [B][V][N] values
  float* outW = out + (size_t)NB * VV * NN;           // [B][N][N] weights
  float* invD = (float*)d_ws;                         // 8*2048 floats (64KB)
  float* scratch = outW;                              // K1 partials live at the
                                                      // head of the weights
                                                      // region; K3 overwrites.

  attn_pass1 <<<dim3(NB * 32 * 4), dim3(256), 0, stream>>>(key, query, value, scratch);
  attn_reduce<<<dim3(NB * 32),     dim3(256), 0, stream>>>(scratch, outV, invD);
  attn_weights<<<dim3(NB * 16 * 16), dim3(256), 0, stream>>>(key, query, invD, outW);
}